// Round 12
// 1662.561 us; speedup vs baseline: 2.8645x; 1.0059x over previous
//
#include <hip/hip_runtime.h>
#include <stdint.h>

#define NOBJ 2048
#define NREL 32768

typedef __attribute__((ext_vector_type(8))) short short8;
typedef __attribute__((ext_vector_type(4))) float f32x4;
typedef __attribute__((ext_vector_type(4))) unsigned short ushort4v;

__device__ __forceinline__ unsigned short f2bs(float x){
  unsigned u = __float_as_uint(x);
  unsigned v = u + 0x7fffu + ((u >> 16) & 1u);
  return (unsigned short)(v >> 16);
}
__device__ __forceinline__ float b2f(unsigned short u){
  return __uint_as_float(((unsigned)u) << 16);
}
__device__ __forceinline__ float sigf(float x){ return 1.0f / (1.0f + expf(-x)); }

// async global->LDS, 16B per lane. LDS dest = wave-uniform base + lane*16.
__device__ __forceinline__ void gload16(const unsigned short* g, unsigned short* l) {
  __builtin_amdgcn_global_load_lds(
      (const __attribute__((address_space(1))) unsigned int*)(uintptr_t)g,
      (__attribute__((address_space(3))) unsigned int*)(uintptr_t)l,
      16, 0, 0);
}

// ====== 128x128 BK=64 engine, depth-2 prefetch (unchanged from r11, passing) ======
template<int RMODE, bool ACCUM, bool OUTB, bool PRODF, bool AF32, bool CINB>
__global__ __launch_bounds__(256, 2)
void gemm_bt(const void* __restrict__ Ap, const unsigned short* __restrict__ B,
             const float* __restrict__ bias, const void* __restrict__ Cin,
             void* __restrict__ Cp, int M, int N, int K, int lda, int ldc,
             const unsigned short* __restrict__ fusedp,
             const int* __restrict__ subp, const int* __restrict__ objp)
{
  __shared__ __align__(16) unsigned short As[2][128 * 64];
  __shared__ __align__(16) unsigned short Bs[2][128 * 64];
  const int t = threadIdx.x;
  const int lane = t & 63;
  const int w = t >> 6;
  const int nwg = gridDim.x;
  const int q8 = nwg >> 3, r8 = nwg & 7;
  const int xcd = blockIdx.x & 7, bidx = blockIdx.x >> 3;
  const int wgid = (xcd < r8 ? xcd * (q8 + 1) : r8 * (q8 + 1) + (xcd - r8) * q8) + bidx;
  const int ntile = N >> 7;
  const int bm = wgid / ntile;
  const int bn = wgid - bm * ntile;
  const int m0 = bm << 7, n0 = bn << 7;
  const int wm = (w & 1) << 6, wn = (w >> 1) << 6;
  const int lrow = lane & 15, kg = lane >> 4;
  const int rx = lrow & 7;

  const int srow8 = lane >> 3;
  const int sslot = ((lane & 7) ^ srow8) << 3;
  const unsigned short* Bg = B + (long)(n0 + w * 8 + srow8) * K + sslot;
  const long ldb32 = (long)32 * K;

  const unsigned short* Ag = nullptr;
  const float* afp = nullptr;
  long lda32 = 0;
  int ar0 = 0, aoff = 0;
  if constexpr (AF32) {
    ar0 = t >> 4;
    const int ac4 = t & 15;
    afp = (const float*)Ap + (long)(m0 + ar0) * lda + (ac4 << 2);
    aoff = (((ac4 >> 1) ^ (ar0 & 7)) << 3) + ((ac4 & 1) << 2);
  } else {
    Ag = (const unsigned short*)Ap + (long)(m0 + w * 8 + srow8) * lda + sslot;
    lda32 = (long)32 * lda;
  }

  const int NT = K >> 6;

  auto stage = [&](int buf, int kt) {
    const unsigned short* bsrc = Bg + (long)kt * 64;
#pragma unroll
    for (int q = 0; q < 4; q++)
      gload16(bsrc + q * ldb32, Bs[buf] + (q * 32 + w * 8) * 64);
    if constexpr (AF32) {
      const float* ap = afp + (long)kt * 64;
#pragma unroll
      for (int j = 0; j < 8; j++) {
        f32x4 v = *(const f32x4*)(ap + (long)j * 16 * lda);
        ushort4v o;
        o[0] = f2bs(v[0]); o[1] = f2bs(v[1]); o[2] = f2bs(v[2]); o[3] = f2bs(v[3]);
        *(ushort4v*)(As[buf] + aoff + (ar0 + j * 16) * 64) = o;
      }
    } else {
      const unsigned short* asrc = Ag + (long)kt * 64;
#pragma unroll
      for (int q = 0; q < 4; q++)
        gload16(asrc + q * lda32, As[buf] + (q * 32 + w * 8) * 64);
    }
  };

  f32x4 acc[4][4] = {};

  stage(0, 0);
  if (NT > 1) stage(1, 1);

  for (int kt = 0; kt < NT; ++kt) {
    const int cur = kt & 1;
    if (kt + 1 < NT) {
      if constexpr (AF32) asm volatile("s_waitcnt vmcnt(4)" ::: "memory");
      else                asm volatile("s_waitcnt vmcnt(8)" ::: "memory");
    } else {
      asm volatile("s_waitcnt vmcnt(0)" ::: "memory");
    }
    asm volatile("s_waitcnt lgkmcnt(0)" ::: "memory");
    __builtin_amdgcn_s_barrier();
    asm volatile("" ::: "memory");

    const unsigned short* As_ = As[cur];
    const unsigned short* Bs_ = Bs[cur];
    short8 afr[4][2], bfr[4][2];
#pragma unroll
    for (int i = 0; i < 4; i++) {
      const int ra = wm + i * 16 + lrow;
#pragma unroll
      for (int ks = 0; ks < 2; ks++)
        afr[i][ks] = *(const short8*)(As_ + ra * 64 + (((ks * 4 + kg) ^ rx) << 3));
    }
#pragma unroll
    for (int j = 0; j < 4; j++) {
      const int rb = wn + j * 16 + lrow;
#pragma unroll
      for (int ks = 0; ks < 2; ks++)
        bfr[j][ks] = *(const short8*)(Bs_ + rb * 64 + (((ks * 4 + kg) ^ rx) << 3));
    }
#pragma unroll
    for (int i = 0; i < 4; i++)
#pragma unroll
      for (int j = 0; j < 4; j++)
#pragma unroll
        for (int ks = 0; ks < 2; ks++)
          acc[i][j] = __builtin_amdgcn_mfma_f32_16x16x32_bf16(afr[i][ks], bfr[j][ks], acc[i][j], 0, 0, 0);
    asm volatile("" ::: "memory");
    __builtin_amdgcn_s_barrier();
    asm volatile("" ::: "memory");
    if (kt + 2 < NT) stage(cur, kt + 2);
  }

  float* Cf = (float*)Cp;
  unsigned short* Cb = (unsigned short*)Cp;
#pragma unroll
  for (int i = 0; i < 4; i++) {
#pragma unroll
    for (int j = 0; j < 4; j++) {
      const int col = n0 + wn + j * 16 + lrow;
      const float bv = bias[col];
#pragma unroll
      for (int q = 0; q < 4; q++) {
        const long row = m0 + wm + i * 16 + kg * 4 + q;
        float v = acc[i][j][q] + bv;
        if constexpr (RMODE == 1) v = fmaxf(v, 0.0f);
        if constexpr (PRODF) {
          int gr = (col < 512) ? subp[row] : objp[row];
          v *= b2f(fusedp[(long)gr * 1024 + col]);
        }
        if constexpr (ACCUM) {
          if constexpr (CINB) v += b2f(((const unsigned short*)Cin)[row * (long)N + col]);
          else                v += ((const float*)Cin)[row * (long)N + col];
        }
        if constexpr (RMODE == 2) v = fmaxf(v, 0.0f);
        if constexpr (OUTB) Cb[row * (long)ldc + col] = f2bs(v);
        else Cf[row * (long)ldc + col] = v;
      }
    }
  }
}

// ============ 64x64 mini engine (r11) + dual-job variant ============
template<int RMODE>
__global__ __launch_bounds__(256, 4)
void gemm64(const unsigned short* __restrict__ A, const unsigned short* __restrict__ B,
            const float* __restrict__ bias, unsigned short* __restrict__ C,
            int M, int N, int K, int lda, int ldc)
{
  __shared__ __align__(16) unsigned short As[2][64 * 64];
  __shared__ __align__(16) unsigned short Bs[2][64 * 64];
  const int t = threadIdx.x;
  const int lane = t & 63;
  const int w = t >> 6;
  const int nwg = gridDim.x;
  const int q8 = nwg >> 3, r8 = nwg & 7;
  const int xcd = blockIdx.x & 7, bidx = blockIdx.x >> 3;
  const int wgid = (xcd < r8 ? xcd * (q8 + 1) : r8 * (q8 + 1) + (xcd - r8) * q8) + bidx;
  const int ntile = N >> 6;
  const int bm = wgid / ntile, bn = wgid - bm * ntile;
  const int m0 = bm << 6, n0 = bn << 6;
  const int wm = (w & 1) << 5, wn = (w >> 1) << 5;
  const int lrow = lane & 15, kg = lane >> 4;
  const int rx = lrow & 7;

  const int srow8 = lane >> 3;
  const int sslot = ((lane & 7) ^ srow8) << 3;
  const unsigned short* Ag = A + (long)(m0 + w * 16 + srow8) * lda + sslot;
  const unsigned short* Bg = B + (long)(n0 + w * 16 + srow8) * K + sslot;
  const long lda8 = 8L * lda, ldb8 = 8L * K;
  const int NT = K >> 6;

  auto stage = [&](int buf, int kt) {
    const unsigned short* a_ = Ag + (long)kt * 64;
    const unsigned short* b_ = Bg + (long)kt * 64;
    gload16(a_,        As[buf] + (w * 16) * 64);
    gload16(a_ + lda8, As[buf] + (w * 16 + 8) * 64);
    gload16(b_,        Bs[buf] + (w * 16) * 64);
    gload16(b_ + ldb8, Bs[buf] + (w * 16 + 8) * 64);
  };

  f32x4 acc[2][2] = {};

  stage(0, 0);
  if (NT > 1) stage(1, 1);

  for (int kt = 0; kt < NT; ++kt) {
    const int cur = kt & 1;
    if (kt + 1 < NT) asm volatile("s_waitcnt vmcnt(4)" ::: "memory");
    else             asm volatile("s_waitcnt vmcnt(0)" ::: "memory");
    __builtin_amdgcn_s_barrier();
    asm volatile("" ::: "memory");

    const unsigned short* As_ = As[cur];
    const unsigned short* Bs_ = Bs[cur];
    short8 afr[2][2], bfr[2][2];
#pragma unroll
    for (int i = 0; i < 2; i++) {
      const int ra = wm + i * 16 + lrow;
#pragma unroll
      for (int ks = 0; ks < 2; ks++)
        afr[i][ks] = *(const short8*)(As_ + ra * 64 + (((ks * 4 + kg) ^ rx) << 3));
    }
#pragma unroll
    for (int j = 0; j < 2; j++) {
      const int rb = wn + j * 16 + lrow;
#pragma unroll
      for (int ks = 0; ks < 2; ks++)
        bfr[j][ks] = *(const short8*)(Bs_ + rb * 64 + (((ks * 4 + kg) ^ rx) << 3));
    }
#pragma unroll
    for (int i = 0; i < 2; i++)
#pragma unroll
      for (int j = 0; j < 2; j++)
#pragma unroll
        for (int ks = 0; ks < 2; ks++)
          acc[i][j] = __builtin_amdgcn_mfma_f32_16x16x32_bf16(afr[i][ks], bfr[j][ks], acc[i][j], 0, 0, 0);
    asm volatile("" ::: "memory");
    __builtin_amdgcn_s_barrier();
    asm volatile("" ::: "memory");
    if (kt + 2 < NT) stage(cur, kt + 2);
  }

#pragma unroll
  for (int i = 0; i < 2; i++) {
#pragma unroll
    for (int j = 0; j < 2; j++) {
      const int col = n0 + wn + j * 16 + lrow;
      const float bv = bias[col];
#pragma unroll
      for (int q = 0; q < 4; q++) {
        const long row = m0 + wm + i * 16 + kg * 4 + q;
        float v = acc[i][j][q] + bv;
        if constexpr (RMODE == 1) v = fmaxf(v, 0.0f);
        C[row * (long)ldc + col] = f2bs(v);
      }
    }
  }
}

// Two same-M/K/lda GEMMs in one launch (runtime relu per job).
__global__ __launch_bounds__(256, 4)
void gemm64_dual(const unsigned short* __restrict__ A1, const unsigned short* __restrict__ B1,
                 const float* __restrict__ bias1, unsigned short* __restrict__ C1,
                 int N1, int ldc1, int rmode1,
                 const unsigned short* __restrict__ A2, const unsigned short* __restrict__ B2,
                 const float* __restrict__ bias2, unsigned short* __restrict__ C2,
                 int N2, int ldc2, int rmode2,
                 int M, int K, int lda)
{
  __shared__ __align__(16) unsigned short As[2][64 * 64];
  __shared__ __align__(16) unsigned short Bs[2][64 * 64];
  const int t = threadIdx.x;
  const int lane = t & 63;
  const int w = t >> 6;
  const int nwg = gridDim.x;
  const int q8 = nwg >> 3, r8 = nwg & 7;
  const int xcd = blockIdx.x & 7, bidx = blockIdx.x >> 3;
  const int wgid = (xcd < r8 ? xcd * (q8 + 1) : r8 * (q8 + 1) + (xcd - r8) * q8) + bidx;

  const int nt1 = (M >> 6) * (N1 >> 6);
  const unsigned short* A; const unsigned short* B;
  const float* bias; unsigned short* C;
  int N, ldc, rmode, tile;
  if (wgid < nt1) { A = A1; B = B1; bias = bias1; C = C1; N = N1; ldc = ldc1; rmode = rmode1; tile = wgid; }
  else            { A = A2; B = B2; bias = bias2; C = C2; N = N2; ldc = ldc2; rmode = rmode2; tile = wgid - nt1; }

  const int ntile = N >> 6;
  const int bm = tile / ntile, bn = tile - bm * ntile;
  const int m0 = bm << 6, n0 = bn << 6;
  const int wm = (w & 1) << 5, wn = (w >> 1) << 5;
  const int lrow = lane & 15, kg = lane >> 4;
  const int rx = lrow & 7;

  const int srow8 = lane >> 3;
  const int sslot = ((lane & 7) ^ srow8) << 3;
  const unsigned short* Ag = A + (long)(m0 + w * 16 + srow8) * lda + sslot;
  const unsigned short* Bg = B + (long)(n0 + w * 16 + srow8) * K + sslot;
  const long lda8 = 8L * lda, ldb8 = 8L * K;
  const int NT = K >> 6;

  auto stage = [&](int buf, int kt) {
    const unsigned short* a_ = Ag + (long)kt * 64;
    const unsigned short* b_ = Bg + (long)kt * 64;
    gload16(a_,        As[buf] + (w * 16) * 64);
    gload16(a_ + lda8, As[buf] + (w * 16 + 8) * 64);
    gload16(b_,        Bs[buf] + (w * 16) * 64);
    gload16(b_ + ldb8, Bs[buf] + (w * 16 + 8) * 64);
  };

  f32x4 acc[2][2] = {};

  stage(0, 0);
  if (NT > 1) stage(1, 1);

  for (int kt = 0; kt < NT; ++kt) {
    const int cur = kt & 1;
    if (kt + 1 < NT) asm volatile("s_waitcnt vmcnt(4)" ::: "memory");
    else             asm volatile("s_waitcnt vmcnt(0)" ::: "memory");
    __builtin_amdgcn_s_barrier();
    asm volatile("" ::: "memory");

    const unsigned short* As_ = As[cur];
    const unsigned short* Bs_ = Bs[cur];
    short8 afr[2][2], bfr[2][2];
#pragma unroll
    for (int i = 0; i < 2; i++) {
      const int ra = wm + i * 16 + lrow;
#pragma unroll
      for (int ks = 0; ks < 2; ks++)
        afr[i][ks] = *(const short8*)(As_ + ra * 64 + (((ks * 4 + kg) ^ rx) << 3));
    }
#pragma unroll
    for (int j = 0; j < 2; j++) {
      const int rb = wn + j * 16 + lrow;
#pragma unroll
      for (int ks = 0; ks < 2; ks++)
        bfr[j][ks] = *(const short8*)(Bs_ + rb * 64 + (((ks * 4 + kg) ^ rx) << 3));
    }
#pragma unroll
    for (int i = 0; i < 2; i++)
#pragma unroll
      for (int j = 0; j < 2; j++)
#pragma unroll
        for (int ks = 0; ks < 2; ks++)
          acc[i][j] = __builtin_amdgcn_mfma_f32_16x16x32_bf16(afr[i][ks], bfr[j][ks], acc[i][j], 0, 0, 0);
    asm volatile("" ::: "memory");
    __builtin_amdgcn_s_barrier();
    asm volatile("" ::: "memory");
    if (kt + 2 < NT) stage(cur, kt + 2);
  }

#pragma unroll
  for (int i = 0; i < 2; i++) {
#pragma unroll
    for (int j = 0; j < 2; j++) {
      const int col = n0 + wn + j * 16 + lrow;
      const float bv = bias[col];
#pragma unroll
      for (int q = 0; q < 4; q++) {
        const long row = m0 + wm + i * 16 + kg * 4 + q;
        float v = acc[i][j][q] + bv;
        if (rmode == 1) v = fmaxf(v, 0.0f);
        C[row * (long)ldc + col] = f2bs(v);
      }
    }
  }
}

// ===================== small kernels =====================

// 13-segment f32->bf16 convert (with optional row padding)
struct SegC { const float* src; unsigned short* dst; long base; long nq; int k0q; int kpq; };
struct Cvt13 { SegC s[13]; long total; };

__global__ void cvt_all(Cvt13 cfg)
{
  for (long i = blockIdx.x * (long)blockDim.x + threadIdx.x; i < cfg.total;
       i += (long)gridDim.x * blockDim.x) {
#pragma unroll
    for (int k = 0; k < 13; k++) {
      if (i >= cfg.s[k].base && i < cfg.s[k].base + cfg.s[k].nq) {
        long q = i - cfg.s[k].base;
        int kpq = cfg.s[k].kpq, k0q = cfg.s[k].k0q;
        long r = q / kpq;
        int kq = (int)(q - r * kpq);
        ushort4v o;
        if (kq < k0q) {
          f32x4 v = *(const f32x4*)(cfg.s[k].src + r * (long)(k0q << 2) + (kq << 2));
          o[0] = f2bs(v[0]); o[1] = f2bs(v[1]); o[2] = f2bs(v[2]); o[3] = f2bs(v[3]);
        } else {
          o[0] = 0; o[1] = 0; o[2] = 0; o[3] = 0;
        }
        *(ushort4v*)(cfg.s[k].dst + r * (long)(kpq << 2) + (kq << 2)) = o;
        break;
      }
    }
  }
}

__global__ void transpose_cvt(const float* __restrict__ src, unsigned short* __restrict__ dst,
                              int R, int C)
{
  __shared__ float tile[32][33];
  int c0 = blockIdx.x * 32, r0 = blockIdx.y * 32;
  for (int i = threadIdx.y; i < 32; i += 8)
    tile[i][threadIdx.x] = src[(long)(r0 + i) * C + c0 + threadIdx.x];
  __syncthreads();
  for (int i = threadIdx.y; i < 32; i += 8)
    dst[(long)(c0 + i) * R + r0 + threadIdx.x] = f2bs(tile[threadIdx.x][i]);
}

__global__ void comp_bias(const float* __restrict__ edgeU_W, const float* __restrict__ up_b,
                          const float* __restrict__ edgeU_b, float* __restrict__ b_comp)
{
  int j = (int)((blockIdx.x * (long)blockDim.x + threadIdx.x) >> 6);
  int l = threadIdx.x & 63;
  if (j >= 512) return;
  float s = 0.0f;
  for (int k = l; k < 2048; k += 64) s += edgeU_W[(long)j * 2048 + k] * up_b[k];
#pragma unroll
  for (int off = 32; off > 0; off >>= 1) s += __shfl_xor(s, off);
  if (l == 0) b_comp[j] = s + edgeU_b[j];
}

// vgbias[j<3072] = j<1536 ? 0 : ngru_bhh[j-1536]; zbias[j<4096] = 0
__global__ void bias_misc(const float* __restrict__ bhh, float* __restrict__ vgbias,
                          float* __restrict__ zbias)
{
  int j = blockIdx.x * blockDim.x + threadIdx.x;
  if (j < 3072) vgbias[j] = (j < 1536) ? 0.0f : bhh[j - 1536];
  if (j < 4096) zbias[j] = 0.0f;
}

__global__ void posembed_k(const float* __restrict__ boxes,
                           const float* __restrict__ w1, const float* __restrict__ b1,
                           const float* __restrict__ g, const float* __restrict__ bb,
                           const float* __restrict__ mm, const float* __restrict__ vv,
                           const float* __restrict__ w2, const float* __restrict__ b2,
                           float* __restrict__ out)
{
  int o = blockIdx.x, t = threadIdx.x;
  __shared__ float e[9];
  __shared__ float p[32];
  if (t == 0) {
    float x1 = boxes[o*4], y1 = boxes[o*4+1], x2 = boxes[o*4+2], y2 = boxes[o*4+3];
    float wdt = x2 - x1 + 1.0f, hgt = y2 - y1 + 1.0f;
    float cx = x1 + 0.5f * wdt, cy = y1 + 0.5f * hgt;
    e[0]=wdt/1024.0f; e[1]=hgt/768.0f; e[2]=cx/1024.0f; e[3]=cy/768.0f;
    e[4]=x1/1024.0f;  e[5]=y1/768.0f;  e[6]=x2/1024.0f; e[7]=y2/768.0f;
    e[8]=wdt*hgt/(1024.0f*768.0f);
  }
  __syncthreads();
  if (t < 32) {
    float s = b1[t];
#pragma unroll
    for (int j = 0; j < 9; j++) s += w1[t*9+j] * e[j];
    s = (s - mm[t]) * g[t] / sqrtf(vv[t] + 1e-5f) + bb[t];
    p[t] = s;
  }
  __syncthreads();
  float s = b2[t];
#pragma unroll
  for (int j = 0; j < 32; j++) s += w2[t*32+j] * p[j];
  out[o*128 + t] = fmaxf(s, 0.0f);
}

__device__ __forceinline__ void pack8_store(unsigned short* dst, f32x4 a, f32x4 b)
{
  ushort4v o0, o1;
  o0[0]=f2bs(a[0]); o0[1]=f2bs(a[1]); o0[2]=f2bs(a[2]); o0[3]=f2bs(a[3]);
  o1[0]=f2bs(b[0]); o1[1]=f2bs(b[1]); o1[2]=f2bs(b[2]); o1[3]=f2bs(b[3]);
  *(ushort4v*)dst = o0;
  *(ushort4v*)(dst + 4) = o1;
}

// merged build_x1 + build_aug
__global__ void build_feed(const float* __restrict__ inst, const float* __restrict__ embd,
                           const float* __restrict__ embl, const int* __restrict__ labels,
                           const float* __restrict__ pose,
                           unsigned short* __restrict__ X1b, unsigned short* __restrict__ augb)
{
  const long T1n = (long)NOBJ * 560;
  const long total = T1n + (long)NOBJ * 608;
  for (long i = blockIdx.x * (long)blockDim.x + threadIdx.x; i < total; i += (long)gridDim.x * blockDim.x) {
    if (i < T1n) {
      int r = (int)(i / 560), c = ((int)(i - (long)r * 560)) << 3;
      unsigned short* dst = X1b + (long)r * 4480 + c;
      const float* src;
      if (c < 4096)      src = inst + (long)r * 4096 + c;
      else if (c < 4296) src = embd + (long)labels[r] * 200 + (c - 4096);
      else if (c < 4424) src = pose + r * 128 + (c - 4296);
      else { ushort4v z = {0,0,0,0}; *(ushort4v*)dst = z; *(ushort4v*)(dst+4) = z; continue; }
      pack8_store(dst, *(const f32x4*)src, *((const f32x4*)src + 1));
    } else {
      long ii = i - T1n;
      int r = (int)(ii / 608), c = ((int)(ii - (long)r * 608)) << 3;
      if (c >= 4296 && c < 4808) continue;
      unsigned short* dst = augb + (long)r * 4864 + c;
      const float* src;
      if (c < 200)       src = embl + (long)labels[r] * 200 + c;
      else if (c < 4296) src = inst + (long)r * 4096 + (c - 200);
      else { ushort4v z = {0,0,0,0}; *(ushort4v*)dst = z; *(ushort4v*)(dst+4) = z; continue; }
      pack8_store(dst, *(const f32x4*)src, *((const f32x4*)src + 1));
    }
  }
}

__device__ __forceinline__ void boxinfo8(const float* __restrict__ bx, float* o)
{
  float x1 = bx[0], y1 = bx[1], x2 = bx[2], y2 = bx[3];
  float wdt = x2 - x1 + 1.0f, hgt = y2 - y1 + 1.0f;
  float cx = x1 + 0.5f * wdt, cy = y1 + 0.5f * hgt;
  const float inv = 1.0f / 1024.0f;
  o[0]=x1*inv; o[1]=y1*inv; o[2]=x2*inv; o[3]=y2*inv;
  o[4]=cx*inv; o[5]=cy*inv; o[6]=wdt*inv; o[7]=hgt*inv;
}

__global__ void build_geo(const float* __restrict__ boxes, const int* __restrict__ sub,
                          const int* __restrict__ obj, unsigned short* __restrict__ geob)
{
  int r = blockIdx.x * blockDim.x + threadIdx.x;
  if (r >= NREL) return;
  float b1[8], b2[8];
  boxinfo8(boxes + sub[r] * 4, b1);
  boxinfo8(boxes + obj[r] * 4, b2);
  float o[32];
#pragma unroll
  for (int j = 0; j < 8; j++) { o[j] = b1[j]; o[8+j] = b2[j]; }
  float ux1 = fminf(b1[0], b2[0]), uy1 = fminf(b1[1], b2[1]);
  float ux2 = fmaxf(b1[2], b2[2]), uy2 = fmaxf(b1[3], b2[3]);
  float uw = ux2 - ux1 + 1.0f, uh = uy2 - uy1 + 1.0f;
  o[16]=ux1; o[17]=uy1; o[18]=ux2; o[19]=uy2;
  o[20]=ux1+0.5f*uw; o[21]=uy1+0.5f*uh; o[22]=uw; o[23]=uh;
  float ix1 = fmaxf(b1[0], b2[0]), iy1 = fmaxf(b1[1], b2[1]);
  float ix2 = fminf(b1[2], b2[2]), iy2 = fminf(b1[3], b2[3]);
  bool bad = (ix2 < ix1) || (iy2 < iy1);
  float iw = ix2 - ix1 + 1.0f, ih = iy2 - iy1 + 1.0f;
  if (bad) {
#pragma unroll
    for (int j = 24; j < 32; j++) o[j] = 0.0f;
  } else {
    o[24]=ix1; o[25]=iy1; o[26]=ix2; o[27]=iy2;
    o[28]=ix1+0.5f*iw; o[29]=iy1+0.5f*ih; o[30]=iw; o[31]=ih;
  }
  unsigned short* gp = geob + (long)r * 64;
#pragma unroll
  for (int j = 0; j < 32; j++) gp[j] = f2bs(o[j]);
#pragma unroll
  for (int j = 32; j < 64; j++) gp[j] = 0;
}

__global__ void gru_init_v(const unsigned short* __restrict__ gi, const float* __restrict__ bhh,
                           float* __restrict__ h, unsigned short* __restrict__ hb, int n)
{
  const long total = (long)n * 64;
  for (long i = blockIdx.x * (long)blockDim.x + threadIdx.x; i < total; i += (long)gridDim.x * blockDim.x) {
    int r = (int)(i >> 6), c = ((int)(i & 63)) << 3;
    const unsigned short* gr = gi + (long)r * 1536;
    short8 vr = *(const short8*)(gr + c);
    short8 vz = *(const short8*)(gr + 512 + c);
    short8 vn = *(const short8*)(gr + 1024 + c);
    float hv[8];
#pragma unroll
    for (int k = 0; k < 8; k++) {
      float rr = sigf(b2f((unsigned short)vr[k]) + bhh[c + k]);
      float z  = sigf(b2f((unsigned short)vz[k]) + bhh[512 + c + k]);
      float nn = tanhf(b2f((unsigned short)vn[k]) + rr * bhh[1024 + c + k]);
      hv[k] = (1.0f - z) * nn;
    }
    float* hp = h + (long)r * 512 + c;
    *(f32x4*)hp = *(f32x4*)hv;
    *(f32x4*)(hp + 4) = *(f32x4*)(hv + 4);
    pack8_store(hb + (long)r * 512 + c, *(f32x4*)hv, *(f32x4*)(hv + 4));
  }
}

// edge GRU init fused with initial ws/wo (one wave per relation)
__global__ __launch_bounds__(256)
void gru_init_e_w(const unsigned short* __restrict__ gi, const float* __restrict__ bhh,
                  unsigned short* __restrict__ edgeb,
                  const unsigned short* __restrict__ vertb,
                  const int* __restrict__ sub, const int* __restrict__ obj,
                  const float* __restrict__ svwW, const float* __restrict__ svwb,
                  const float* __restrict__ ovwW, const float* __restrict__ ovwb,
                  float* __restrict__ ws_arr, float* __restrict__ wo_arr, int n)
{
  long gid = blockIdx.x * 256L + threadIdx.x;
  int r = (int)(gid >> 6);
  int l = (int)(gid & 63);
  if (r >= n) return;
  const int c = l << 3;
  const unsigned short* gr = gi + (long)r * 1536;
  short8 vr = *(const short8*)(gr + c);
  short8 vz = *(const short8*)(gr + 512 + c);
  short8 vn = *(const short8*)(gr + 1024 + c);
  float hv[8];
#pragma unroll
  for (int k = 0; k < 8; k++) {
    float rr = sigf(b2f((unsigned short)vr[k]) + bhh[c + k]);
    float z  = sigf(b2f((unsigned short)vz[k]) + bhh[512 + c + k]);
    float nn = tanhf(b2f((unsigned short)vn[k]) + rr * bhh[1024 + c + k]);
    hv[k] = (1.0f - z) * nn;
  }
  pack8_store(edgeb + (long)r * 512 + c, *(f32x4*)hv, *(f32x4*)(hv + 4));
  int s = sub[r], o = obj[r];
  short8 svv = *(const short8*)(vertb + (long)s * 512 + c);
  short8 ovv = *(const short8*)(vertb + (long)o * 512 + c);
  float as = 0.0f, ao = 0.0f;
#pragma unroll
  for (int k = 0; k < 8; k++) {
    float e = hv[k];
    as += svwW[c + k] * b2f((unsigned short)svv[k]) + svwW[512 + c + k] * e;
    ao += ovwW[c + k] * b2f((unsigned short)ovv[k]) + ovwW[512 + c + k] * e;
  }
#pragma unroll
  for (int off = 32; off > 0; off >>= 1) {
    as += __shfl_xor(as, off);
    ao += __shfl_xor(ao, off);
  }
  if (l == 0) {
    ws_arr[r] = sigf(as + svwb[0]);
    wo_arr[r] = sigf(ao + ovwb[0]);
  }
}

__global__ void gru_step_v(const unsigned short* __restrict__ gi, const unsigned short* __restrict__ gh,
                           int ghs, const float* __restrict__ hin, float* __restrict__ hout,
                           unsigned short* __restrict__ hb, int n)
{
  const long total = (long)n * 64;
  for (long i = blockIdx.x * (long)blockDim.x + threadIdx.x; i < total; i += (long)gridDim.x * blockDim.x) {
    int r = (int)(i >> 6), c = ((int)(i & 63)) << 3;
    const unsigned short* gr = gi + (long)r * 1536;
    const unsigned short* hr = gh + (long)r * ghs;
    short8 ir = *(const short8*)(gr + c);
    short8 iz = *(const short8*)(gr + 512 + c);
    short8 in_ = *(const short8*)(gr + 1024 + c);
    short8 hrr = *(const short8*)(hr + c);
    short8 hz = *(const short8*)(hr + 512 + c);
    short8 hn = *(const short8*)(hr + 1024 + c);
    const float* hi = hin + (long)r * 512 + c;
    f32x4 h0 = *(const f32x4*)hi;
    f32x4 h1 = *(const f32x4*)(hi + 4);
    float hv[8];
#pragma unroll
    for (int k = 0; k < 8; k++) {
      float rr = sigf(b2f((unsigned short)ir[k]) + b2f((unsigned short)hrr[k]));
      float z  = sigf(b2f((unsigned short)iz[k]) + b2f((unsigned short)hz[k]));
      float nn = tanhf(b2f((unsigned short)in_[k]) + rr * b2f((unsigned short)hn[k]));
      float old = (k < 4) ? h0[k] : h1[k - 4];
      hv[k] = (1.0f - z) * nn + z * old;
    }
    float* hp = hout + (long)r * 512 + c;
    *(f32x4*)hp = *(f32x4*)hv;
    *(f32x4*)(hp + 4) = *(f32x4*)(hv + 4);
    pack8_store(hb + (long)r * 512 + c, *(f32x4*)hv, *(f32x4*)(hv + 4));
  }
}

__global__ __launch_bounds__(256)
void gru_step_e2(const unsigned short* __restrict__ GH, const unsigned short* __restrict__ VG,
                 const float* __restrict__ ws_arr_in, const float* __restrict__ wo_arr_in,
                 float* __restrict__ ws_arr_out, float* __restrict__ wo_arr_out,
                 const int* __restrict__ sub, const int* __restrict__ obj,
                 const float* __restrict__ bih,
                 unsigned short* __restrict__ edgeb, float* __restrict__ fout,
                 const unsigned short* __restrict__ vertb,
                 const float* __restrict__ svwW, const float* __restrict__ svwb,
                 const float* __restrict__ ovwW, const float* __restrict__ ovwb,
                 int compute_w, int n)
{
  long gid = blockIdx.x * 256L + threadIdx.x;
  int r = (int)(gid >> 6);
  int l = (int)(gid & 63);
  if (r >= n) return;
  const int c = l << 3;
  int s = sub[r], o = obj[r];
  float ws = ws_arr_in[r], wo = wo_arr_in[r];
  const unsigned short* gh = GH + (long)r * 1536;
  const unsigned short* vs = VG + (long)s * 3072;
  const unsigned short* vo = VG + (long)o * 3072;
  short8 ghr = *(const short8*)(gh + c);
  short8 ghz = *(const short8*)(gh + 512 + c);
  short8 ghn = *(const short8*)(gh + 1024 + c);
  short8 vsr = *(const short8*)(vs + c);
  short8 vsz = *(const short8*)(vs + 512 + c);
  short8 vsn = *(const short8*)(vs + 1024 + c);
  short8 vor_ = *(const short8*)(vo + c);
  short8 voz = *(const short8*)(vo + 512 + c);
  short8 von = *(const short8*)(vo + 1024 + c);
  short8 hold = *(const short8*)(edgeb + (long)r * 512 + c);
  float hv[8];
#pragma unroll
  for (int k = 0; k < 8; k++) {
    float gir = ws * b2f((unsigned short)vsr[k]) + wo * b2f((unsigned short)vor_[k]) + bih[c + k];
    float giz = ws * b2f((unsigned short)vsz[k]) + wo * b2f((unsigned short)voz[k]) + bih[512 + c + k];
    float gin = ws * b2f((unsigned short)vsn[k]) + wo * b2f((unsigned short)von[k]) + bih[1024 + c + k];
    float rr = sigf(gir + b2f((unsigned short)ghr[k]));
    float z  = sigf(giz + b2f((unsigned short)ghz[k]));
    float nn = tanhf(gin + rr * b2f((unsigned short)ghn[k]));
    hv[k] = (1.0f - z) * nn + z * b2f((unsigned short)hold[k]);
  }
  pack8_store(edgeb + (long)r * 512 + c, *(f32x4*)hv, *(f32x4*)(hv + 4));
  if (fout) {
    float* fp = fout + (long)r * 512 + c;
    *(f32x4*)fp = *(f32x4*)hv;
    *(f32x4*)(fp + 4) = *(f32x4*)(hv + 4);
  }
  if (compute_w) {
    short8 svv = *(const short8*)(vertb + (long)s * 512 + c);
    short8 ovv = *(const short8*)(vertb + (long)o * 512 + c);
    float as = 0.0f, ao = 0.0f;
#pragma unroll
    for (int k = 0; k < 8; k++) {
      float e = hv[k];
      as += svwW[c + k] * b2f((unsigned short)svv[k]) + svwW[512 + c + k] * e;
      ao += ovwW[c + k] * b2f((unsigned short)ovv[k]) + ovwW[512 + c + k] * e;
    }
#pragma unroll
    for (int off = 32; off > 0; off >>= 1) {
      as += __shfl_xor(as, off);
      ao += __shfl_xor(ao, off);
    }
    if (l == 0) {
      ws_arr_out[r] = sigf(as + svwb[0]);
      wo_arr_out[r] = sigf(ao + ovwb[0]);
    }
  }
}

// ===================== CSR =====================

__global__ void csr_count(const int* __restrict__ sub, const int* __restrict__ obj,
                          int* __restrict__ cnt)
{
  int r = blockIdx.x * blockDim.x + threadIdx.x;
  if (r >= NREL) return;
  atomicAdd(&cnt[sub[r]], 1);
  atomicAdd(&cnt[obj[r]], 1);
}

__global__ __launch_bounds__(1024)
void csr_scan(const int* __restrict__ cnt, int* __restrict__ off)
{
  __shared__ int a[1024], b[1024];
  int t = threadIdx.x;
  int c0 = cnt[2*t], c1 = cnt[2*t+1];
  a[t] = c0 + c1;
  __syncthreads();
  int* src = a; int* dst = b;
  for (int s = 1; s < 1024; s <<= 1) {
    int v = src[t];
    if (t >= s) v += src[t - s];
    dst[t] = v;
    __syncthreads();
    int* tmp = src; src = dst; dst = tmp;
  }
  int incl = src[t];
  int excl = incl - (c0 + c1);
  off[2*t] = excl;
  off[2*t+1] = excl + c0;
  if (t == 1023) off[2048] = incl;
}

__global__ void csr_fill(const int* __restrict__ sub, const int* __restrict__ obj,
                         const int* __restrict__ off, int* __restrict__ rcur,
                         int* __restrict__ lists)
{
  int r = blockIdx.x * blockDim.x + threadIdx.x;
  if (r >= NREL) return;
  int s = sub[r];
  int p = atomicAdd(&rcur[s], 1);
  lists[off[s] + p] = (r << 1);
  int o = obj[r];
  int q = atomicAdd(&rcur[o], 1);
  lists[off[o] + q] = (r << 1) | 1;
}

__global__ __launch_bounds__(128)
void ctx_gather(const unsigned short* __restrict__ edgeb, const float* __restrict__ ws,
                const float* __restrict__ wo, const int* __restrict__ off,
                const int* __restrict__ lists, unsigned short* __restrict__ ctxb)
{
  __shared__ float part[512];
  int o = blockIdx.x;
  int l = threadIdx.x & 63;
  int w = threadIdx.x >> 6;
  int i0 = off[o], i1 = off[o + 1];
  float acc[8] = {0.f,0.f,0.f,0.f,0.f,0.f,0.f,0.f};
  for (int i = i0 + w; i < i1; i += 2) {
    int e = lists[i];
    int r = e >> 1;
    float sc = (e & 1) ? wo[r] : ws[r];
    short8 row = *(const short8*)(edgeb + (long)r * 512 + l * 8);
#pragma unroll
    for (int k = 0; k < 8; k++) acc[k] += sc * b2f((unsigned short)row[k]);
  }
  if (w == 1) {
    *(f32x4*)&part[l*8]     = *(f32x4*)&acc[0];
    *(f32x4*)&part[l*8 + 4] = *(f32x4*)&acc[4];
  }
  __syncthreads();
  if (w == 0) {
#pragma unroll
    for (int k = 0; k < 8; k++) acc[k] += part[l*8 + k];
    pack8_store(ctxb + (long)o * 512 + l * 8, *(f32x4*)&acc[0], *(f32x4*)&acc[4]);
  }
}

// ===================== driver =====================

static inline int nblk(long total) {
  long b = (total + 255) / 256;
  return (int)(b > 16384 ? 16384 : b);
}

#define GEMM(RM, AC, OB, PF, grid, Aa, Bb, bb, Ci, Cc, Mm, Nn, Kk, ldA, ldC, fp, sp, op) \
  gemm_bt<RM, AC, OB, PF, false, false><<<grid, 256, 0, stream>>>(Aa, Bb, bb, Ci, Cc, Mm, Nn, Kk, ldA, ldC, fp, sp, op)
#define GEMMCB(RM, grid, Aa, Bb, bb, Ci, Cc, Mm, Nn, Kk, ldA, ldC) \
  gemm_bt<RM, true, true, false, false, true><<<grid, 256, 0, stream>>>(Aa, Bb, bb, Ci, Cc, Mm, Nn, Kk, ldA, ldC, nullptr, nullptr, nullptr)
#define GEMMF(RM, grid, Aa, Bb, bb, Cc, Mm, Nn, Kk, ldA, ldC) \
  gemm_bt<RM, false, true, false, true, false><<<grid, 256, 0, stream>>>(Aa, Bb, bb, nullptr, Cc, Mm, Nn, Kk, ldA, ldC, nullptr, nullptr, nullptr)
#define G64(RM, Aa, Bb, bb, Cc, Mm, Nn, Kk, ldA, ldC) \
  gemm64<RM><<<dim3(((Mm) >> 6) * ((Nn) >> 6)), 256, 0, stream>>>(Aa, Bb, bb, Cc, Mm, Nn, Kk, ldA, ldC)

extern "C" void kernel_launch(void* const* d_in, const int* in_sizes, int n_in,
                              void* d_out, int out_size, void* d_ws, size_t ws_size,
                              hipStream_t stream)
{
  const float* inst     = (const float*)d_in[0];
  const float* unionf   = (const float*)d_in[1];
  const float* boxes    = (const float*)d_in[2];
  const float* embd_W   = (const float*)d_in[3];
  const float* embl_W   = (const float*)d_in[4];
  const float* up_W     = (const float*)d_in[5];
  const float* up_b     = (const float*)d_in[6];
  const float* pairup_W = (const float*)d_in[7];
  const float* pairup_b = (const float*)d_in[8];
  const float* pos1_W   = (const float*)d_in[9];
  const float* pos1_b   = (const float*)d_in[10];
  const float* bn_g     = (const float*)d_in[11];
  const float* bn_b     = (const float*)d_in[12];
  const float* bn_m     = (const float*)d_in[13];
  const float* bn_v     = (const float*)d_in[14];
  const float* pos2_W   = (const float*)d_in[15];
  const float* pos2_b   = (const float*)d_in[16];
  const float* spt1_W   = (const float*)d_in[17];
  const float* spt1_b   = (const float*)d_in[18];
  const float* spt2_W   = (const float*)d_in[19];
  const float* spt2_b   = (const float*)d_in[20];
  const float* pairfin_W= (const float*)d_in[21];
  const float* pairfin_b= (const float*)d_in[22];
  const float* objhid_W = (const float*)d_in[23];
  const float* objhid_b = (const float*)d_in[24];
  const float* objfin_W = (const float*)d_in[25];
  const float* objfin_b = (const float*)d_in[26];
  const float* objU_W   = (const float*)d_in[27];
  const float* objU_b   = (const float*)d_in[28];
  const float* edgeU_W  = (const float*)d_in[29];
  const float* edgeU_b  = (const float*)d_in[30];
  const float* egru_Wih = (const float*)d_in[31];
  const float* egru_Whh = (const float*)d_in[32];
  const float* egru_bih = (const float*)d_in[33];
  const float* egru_bhh = (const float*)d_in[34];
  const float* ngru_Wih = (const float*)d_in[35];
  const float* ngru_Whh = (const float*)d_in[36];
  const float* ngru_bih = (const float*)d_in[37];
  const float* ngru_bhh = (const float*)d_in[38];
  const float* svw_W    = (const float*)d_in[39];
  const float* svw_b    = (const float*)d_in[40];
  const float* ovw_W    = (const float*)d_in[41];
  const float* ovw_b    = (const float*)d_in[42];
  const int*   labels   = (const int*)d_in[43];
  const int*   sub      = (const int*)d_in[44];
  const int*   obj      = (const int*)d_in[45];
  (void)in_sizes; (void)n_in; (void)out_size; (void)ws_size;

  char* base = (char*)d_ws;
  size_t off = 0;
  auto alloc = [&](size_t bytes) -> void* {
    void* p = base + off;
    off += (bytes + 255) & ~(size_t)255;
    return p;
  };

  // ---- weights (bf16) ----
  unsigned short* objhid_Wb  = (unsigned short*)alloc(512L  * 4480 * 2);
  unsigned short* pairup_Wb  = (unsigned short*)alloc(1024L * 4864 * 2);
  unsigned short* objfin_Wb  = (unsigned short*)alloc(2048L * 4864 * 2);
  unsigned short* up_Wtb     = (unsigned short*)alloc(4096L * 2048 * 2);
  unsigned short* pairfin_Wb = (unsigned short*)alloc(2048L * 1024 * 2);
  unsigned short* spt1_Wb    = (unsigned short*)alloc(512L  * 64   * 2);
  unsigned short* spt2_Wb    = (unsigned short*)alloc(1024L * 512  * 2);
  unsigned short* objU_Wb    = (unsigned short*)alloc(512L  * 2048 * 2);
  unsigned short* edgeU_Wb   = (unsigned short*)alloc(512L  * 2048 * 2);
  unsigned short* egru_Wihb  = (unsigned short*)alloc(1536L * 512  * 2);
  unsigned short* egru_Whhb  = (unsigned short*)alloc(1536L * 512  * 2);
  unsigned short* ngru_Wihb  = (unsigned short*)alloc(1536L * 512  * 2);
  unsigned short* vg_Wb      = (unsigned short*)alloc(3072L * 512  * 2);
  unsigned short* W_compb    = (unsigned short*)alloc(512L  * 4096 * 2);
  float*          b_comp     = (float*)alloc(512L * 4);
  float*          zbias      = (float*)alloc(4096L * 4);
  float*          vgbias     = (float*)alloc(3072L * 4);

  // ---- activations ----
  float*          pose      = (float*)alloc(NOBJ * 128L * 4);
  unsigned short* obj_featsb= (unsigned short*)alloc((long)NOBJ * 2048 * 2);
  unsigned short* obj_repb  = (unsigned short*)alloc((long)NOBJ * 512 * 2);
  unsigned short* giv       = (unsigned short*)alloc((long)NOBJ * 1536 * 2);
  unsigned short* VGb       = (unsigned short*)alloc((long)NOBJ * 3072 * 2);
  float*          vert      = (float*)alloc((long)NOBJ * 512 * 4);
  unsigned short* vertb     = (unsigned short*)alloc((long)NOBJ * 512 * 2);
  unsigned short* ctxb      = (unsigned short*)alloc((long)NOBJ * 512 * 2);
  unsigned short* geob      = (unsigned short*)alloc((long)NREL * 64 * 2);
  unsigned short* edgeb     = (unsigned short*)alloc((long)NREL * 512 * 2);
  float*          ws_arr    = (float*)alloc((long)NREL * 4);
  float*          wo_arr    = (float*)alloc((long)NREL * 4);

  // CSR (cnt,rcur adjacent -> single memset)
  int* cnt   = (int*)alloc(NOBJ * 4);
  int* rcur  = (int*)alloc(NOBJ * 4);
  int* coff  = (int*)alloc((NOBJ + 1) * 4);
  int* lists = (int*)alloc(2L * NREL * 4);

  // REGION_A: X1b -> T1b (bf16 NRELx512)
  char* regA = (char*)alloc((long)NREL * 512 * 4);
  unsigned short* X1b = (unsigned short*)regA;
  unsigned short* T1b = (unsigned short*)regA;
  // REGION_B: augb -> rel_repb
  char* regB = (char*)alloc((long)NOBJ * 4864 * 2 > (long)NREL * 512 * 2
                            ? (long)NOBJ * 4864 * 2 : (long)NREL * 512 * 2);
  unsigned short* augb     = (unsigned short*)regB;
  unsigned short* rel_repb = (unsigned short*)regB;
  unsigned short* fusedb = (unsigned short*)alloc((long)NOBJ * 1024 * 2);
  unsigned short* spt1b  = (unsigned short*)alloc((long)NREL * 512 * 2);
  // BIG1: [G1 128MB | prodb 64MB] -> gi_e(init) -> GH
  char* big1 = (char*)alloc((long)NREL * 1536 * 4);
  unsigned short* G1    = (unsigned short*)big1;
  unsigned short* prodb = (unsigned short*)(big1 + (long)NREL * 1024 * 4);
  unsigned short* gi_e  = (unsigned short*)big1;
  unsigned short* GHb   = (unsigned short*)big1;

  float* d_out_vert = (float*)d_out;
  float* d_out_edge = (float*)d_out + (long)NOBJ * 512;

  // ---- weight conversions: ONE kernel, 13 segments ----
  {
    Cvt13 cfg;
    long b = 0;
    auto seg = [&](int k, const float* s, unsigned short* d, long rows, int K0, int Kp) {
      cfg.s[k].src = s; cfg.s[k].dst = d; cfg.s[k].base = b;
      cfg.s[k].k0q = K0 >> 2; cfg.s[k].kpq = Kp >> 2;
      cfg.s[k].nq = rows * (long)(Kp >> 2);
      b += cfg.s[k].nq;
    };
    seg(0,  objhid_W,  objhid_Wb,  512,  4424, 4480);
    seg(1,  pairup_W,  pairup_Wb,  1024, 4808, 4864);
    seg(2,  objfin_W,  objfin_Wb,  2048, 4808, 4864);
    seg(3,  spt1_W,    spt1_Wb,    512,  32,   64);
    seg(4,  pairfin_W, pairfin_Wb, 2048, 1024, 1024);
    seg(5,  spt2_W,    spt2_Wb,    1024, 512,  512);
    seg(6,  objU_W,    objU_Wb,    512,  2048, 2048);
    seg(7,  edgeU_W,   edgeU_Wb,   512,  2048, 2048);
    seg(8,  egru_Wih,  egru_Wihb,  1536, 512,  512);
    seg(9,  egru_Whh,  egru_Whhb,  1536, 512,  512);
    seg(10, ngru_Wih,  ngru_Wihb,  1536, 512,  512);
    seg(11, egru_Wih,  vg_Wb,              1536, 512, 512);
    seg(12, ngru_Whh,  vg_Wb + 1536L*512,  1536, 512, 512);
    cfg.total = b;
    cvt_all<<<nblk(b), 256, 0, stream>>>(cfg);
  }
  bias_misc<<<16, 256, 0, stream>>>(ngru_bhh, vgbias, zbias);
  transpose_cvt<<<dim3(4096/32, 2048/32), dim3(32, 8), 0, stream>>>(up_W, up_Wtb, 2048, 4096);
  comp_bias<<<128, 256, 0, stream>>>(edgeU_W, up_b, edgeU_b, b_comp);
  G64(0, edgeU_Wb, up_Wtb, zbias, W_compb, 512, 4096, 2048, 2048, 4096);

  // ---- CSR build ----
  hipMemsetAsync(cnt, 0, 2L * NOBJ * 4, stream);   // cnt + rcur
  csr_count<<<NREL/256, 256, 0, stream>>>(sub, obj, cnt);
  csr_scan<<<1, 1024, 0, stream>>>(cnt, coff);
  csr_fill<<<NREL/256, 256, 0, stream>>>(sub, obj, coff, rcur, lists);

  // ---- object stream ----
  posembed_k<<<NOBJ, 128, 0, stream>>>(boxes, pos1_W, pos1_b, bn_g, bn_b, bn_m, bn_v,
                                       pos2_W, pos2_b, pose);
  build_feed<<<nblk((long)NOBJ*(560+608)), 256, 0, stream>>>(inst, embd_W, embl_W, labels, pose,
                                                             X1b, augb);
  G64(0, X1b, objhid_Wb, objhid_b, augb + 4296, NOBJ, 512, 4480, 4480, 4864);
  // pairup + objfin share A=augb: one dual launch
  gemm64_dual<<<dim3((NOBJ>>6)*((1024+2048)>>6)), 256, 0, stream>>>(
      augb, pairup_Wb, pairup_b, fusedb,     1024, 1024, 0,
      augb, objfin_Wb, objfin_b, obj_featsb, 2048, 2048, 1,
      NOBJ, 4864, 4864);
  G64(0, obj_featsb, objU_Wb, objU_b, obj_repb, NOBJ, 512, 2048, 2048, 512);
  G64(0, obj_repb, ngru_Wihb, ngru_bih, giv, NOBJ, 1536, 512, 512, 1536);
  gru_init_v<<<nblk((long)NOBJ*64), 256, 0, stream>>>(giv, ngru_bhh, vert, vertb, NOBJ);

  // ---- relation stream ----
  build_geo<<<(NREL + 255) / 256, 256, 0, stream>>>(boxes, sub, obj, geob);
  GEMM(1,false,true ,false, dim3((NREL>>7)*(512>>7)),  geob, spt1_Wb, spt1_b, nullptr, spt1b, NREL, 512, 64, 64, 512, nullptr, nullptr, nullptr);
  GEMM(1,false,true ,true , dim3((NREL>>7)*(1024>>7)), spt1b, spt2_Wb, spt2_b, nullptr, prodb, NREL, 1024, 512, 512, 1024, fusedb, sub, obj);
  GEMM(1,false,true ,false, dim3((NREL>>7)*(2048>>7)), prodb, pairfin_Wb, pairfin_b, nullptr, G1, NREL, 2048, 1024, 1024, 2048, nullptr, nullptr, nullptr);
  GEMMF(0, dim3((NREL>>7)*(512>>7)), unionf, W_compb, b_comp, T1b, NREL, 512, 4096, 4096, 512);
  GEMMCB(2, dim3((NREL>>7)*(512>>7)), G1, edgeU_Wb, zbias, T1b, rel_repb, NREL, 512, 2048, 2048, 512);
  GEMM(0,false,true ,false, dim3((NREL>>7)*(1536>>7)), rel_repb, egru_Wihb, egru_bih, nullptr, gi_e, NREL, 1536, 512, 512, 1536, nullptr, nullptr, nullptr);
  // edge GRU init + initial ws/wo fused
  gru_init_e_w<<<NREL*64/256, 256, 0, stream>>>(gi_e, egru_bhh, edgeb, vertb, sub, obj,
                                                svw_W, svw_b, ovw_W, ovw_b, ws_arr, wo_arr, NREL);

  // ---- message-passing loop ----
  for (int it = 0; it < 3; it++) {
    const bool last = (it == 2);
    ctx_gather<<<NOBJ, 128, 0, stream>>>(edgeb, ws_arr, wo_arr, coff, lists, ctxb);
    // VG (vertb) + giv (ctxb) in one dual launch
    gemm64_dual<<<dim3((NOBJ>>6)*((3072+1536)>>6)), 256, 0, stream>>>(
        vertb, vg_Wb,     vgbias,   VGb, 3072, 3072, 0,
        ctxb,  ngru_Wihb, ngru_bih, giv, 1536, 1536, 0,
        NOBJ, 512, 512);
    GEMM(0,false,true,false, dim3((NREL>>7)*(1536>>7)), edgeb, egru_Whhb, egru_bhh, nullptr, GHb, NREL, 1536, 512, 512, 1536, nullptr, nullptr, nullptr);
    gru_step_v<<<nblk((long)NOBJ*64), 256, 0, stream>>>(giv, VGb + 1536, 3072, vert,
                                                        last ? d_out_vert : vert, vertb, NOBJ);
    gru_step_e2<<<NREL*64/256, 256, 0, stream>>>(GHb, VGb, ws_arr, wo_arr, ws_arr, wo_arr,
                                                 sub, obj, egru_bih, edgeb,
                                                 last ? d_out_edge : nullptr, vertb,
                                                 svw_W, svw_b, ovw_W, ovw_b,
                                                 last ? 0 : 1, NREL);
  }
}